// Round 2
// baseline (205.884 us; speedup 1.0000x reference)
//
#include <hip/hip_runtime.h>

// Problem constants (match reference)
#define B_ 8
#define H_ 512
#define W_ 1024
#define HW_ (H_ * W_)
#define G_ 104857
#define N_ (B_ * G_)
#define GBLK_ 410               // ceil(G_/256)
#define EPS_ 1e-6f
#define DCOS_ 0.867f
#define DDIFF_ 0.005f
#define DZ_ 1e-5f
#define SENT_ 0xFFFFFFFFu
#define NO_R_ 0xFFFFFFFFu

// ws layout (byte offsets); [0, ZERO_BYTES) zeroed by one memset per call
#define OFF_BINS0   0      // 256 u32  (pass-1 hist, fused into compute)
#define OFF_BINS1   1024   // 256 u32
#define OFF_BINS2   2048   // 256 u32
#define OFF_BINS3   3072   // 256 u32  (4th-byte counts within the 24-bit bin)
#define OFF_BINSUM3 4096   // 256 f64  (4th-byte value sums within the bin)
#define OFF_SUMHI   6144   // f64
#define OFF_CNTHI   6152   // u32
#define OFF_DONE    6156   // u32
#define OFF_KEYS    8192   // N_ u32
#define ZERO_BYTES  8192

struct F3 { float x, y, z; };
__device__ __forceinline__ F3 f3sub(F3 a, F3 b) { return {a.x - b.x, a.y - b.y, a.z - b.z}; }
__device__ __forceinline__ float f3dot(F3 a, F3 b) { return a.x * b.x + a.y * b.y + a.z * b.z; }
__device__ __forceinline__ F3 f3cross(F3 a, F3 b) {
    return {a.y * b.z - a.z * b.y, a.z * b.x - a.x * b.z, a.x * b.y - a.y * b.x};
}

// Block-redundant scan+pick over a 256-bin global histogram.
// All 256 threads participate. s must be LDS[258]. r_in==NO_R_ -> use total/4.
// Returns selected byte, residual rank within that byte's bin, and total count.
__device__ __forceinline__ void
scan_pick(const unsigned int* __restrict__ bins, unsigned int* s, unsigned int r_in,
          unsigned int& byte, unsigned int& rank, unsigned int& total)
{
    int t = threadIdx.x;
    s[t] = bins[t];
    if (t == 0) { s[256] = 0u; s[257] = 0u; }
    __syncthreads();
    for (int off = 1; off < 256; off <<= 1) {
        unsigned int add = (t >= off) ? s[t - off] : 0u;
        __syncthreads();
        s[t] += add;
        __syncthreads();
    }
    unsigned int tot = s[255];
    unsigned int r = (r_in == NO_R_) ? (tot / 4u) : r_in;
    unsigned int csum = s[t];
    unsigned int cprev = (t == 0) ? 0u : s[t - 1];
    if (csum > r && cprev <= r) { s[256] = (unsigned int)t; s[257] = r - cprev; }
    __syncthreads();
    byte = s[256]; rank = s[257]; total = tot;
    __syncthreads();  // s reusable after return
}

// loss + valid per triplet; writes orderable key; fused MSB histogram.
// 1D grid; blockIdx.x & 7 = image -> same image stays on one XCD (round-robin
// block->XCD dispatch), so its 4 MB of depth maps fits that XCD's 4 MiB L2.
__global__ void __launch_bounds__(256)
compute_kernel(const float* __restrict__ pred, const float* __restrict__ targ,
               const float* __restrict__ intr,
               const int* __restrict__ p1, const int* __restrict__ p2,
               const int* __restrict__ p3,
               unsigned int* __restrict__ keys, unsigned int* __restrict__ bins0)
{
    __shared__ unsigned int lbins[256];
    lbins[threadIdx.x] = 0;
    __syncthreads();

    int b = blockIdx.x & 7;
    int g = (blockIdx.x >> 3) * 256 + threadIdx.x;
    if (g < G_) {
        float f  = intr[b * 9 + 0];   // fx used for both x and y (per reference)
        float u0 = intr[b * 9 + 2];
        float v0 = intr[b * 9 + 5];
        int i1 = p1[b * G_ + g], i2 = p2[b * G_ + g], i3 = p3[b * G_ + g];
        const float* tb = targ + (size_t)b * HW_;
        const float* pb = pred + (size_t)b * HW_;

        auto unproj = [&](const float* dmap, int i) -> F3 {
            float d = dmap[i];
            float u = (float)(i & (W_ - 1));
            float v = (float)(i >> 10);
            F3 P;
            P.x = (u - u0) * d / f;
            P.y = (v - v0) * d / f;
            P.z = d;
            return P;
        };

        F3 G1 = unproj(tb, i1), G2 = unproj(tb, i2), G3 = unproj(tb, i3);
        F3 P1 = unproj(pb, i1), P2 = unproj(pb, i2), P3 = unproj(pb, i3);

        // ---- filter_mask on GT groups ----
        F3 d12 = f3sub(G2, G1), d13 = f3sub(G3, G1), d23 = f3sub(G3, G2);
        float e11 = f3dot(d12, d12), e22 = f3dot(d13, d13), e33 = f3dot(d23, d23);
        float e12 = f3dot(d12, d13), e13 = f3dot(d12, d23), e23 = f3dot(d13, d23);
        float q1 = sqrtf(e11), q2 = sqrtf(e22), q3 = sqrtf(e33);
        int cnt = 0;
        cnt += (fabsf(e11 / (q1 * q1 + EPS_)) > DCOS_) ? 1 : 0;
        cnt += (fabsf(e22 / (q2 * q2 + EPS_)) > DCOS_) ? 1 : 0;
        cnt += (fabsf(e33 / (q3 * q3 + EPS_)) > DCOS_) ? 1 : 0;
        cnt += (fabsf(e12 / (q1 * q2 + EPS_)) > DCOS_) ? 2 : 0;  // symmetric off-diag
        cnt += (fabsf(e13 / (q1 * q3 + EPS_)) > DCOS_) ? 2 : 0;
        cnt += (fabsf(e23 / (q2 * q3 + EPS_)) > DCOS_) ? 2 : 0;
        bool mask_cos = cnt > 3;
        bool mask_pad = (G1.z > DZ_) && (G2.z > DZ_) && (G3.z > DZ_);
        bool mx = (fabsf(d12.x) < DDIFF_) || (fabsf(d13.x) < DDIFF_) || (fabsf(d23.x) < DDIFF_);
        bool my = (fabsf(d12.y) < DDIFF_) || (fabsf(d13.y) < DDIFF_) || (fabsf(d23.y) < DDIFF_);
        bool mz = (fabsf(d12.z) < DDIFF_) || (fabsf(d13.z) < DDIFF_) || (fabsf(d23.z) < DDIFF_);
        bool valid = mask_pad && !((mx && my && mz) || mask_cos);

        // faithful replication of the reference's boolean-mask broadcast quirk
        bool c0 = (P1.z == 0.0f), c1 = (P2.z == 0.0f), c2 = (P3.z == 0.0f);
        if (c0) { P1.x = 1e-4f; P2.x = 1e-4f; P3.x = 1e-4f; }
        if (c1) { P1.y = 1e-4f; P2.y = 1e-4f; P3.y = 1e-4f; }
        if (c2) { P1.z = 1e-4f; P2.z = 1e-4f; P3.z = 1e-4f; }

        auto vnormal = [](F3 A, F3 Bp, F3 C) -> F3 {
            F3 a = f3sub(Bp, A), c = f3sub(C, A);
            F3 n = f3cross(a, c);
            float nn = sqrtf(f3dot(n, n));
            nn = nn + ((nn == 0.0f) ? EPS_ : 0.0f);
            return F3{n.x / nn, n.y / nn, n.z / nn};
        };
        F3 ng = vnormal(G1, G2, G3);
        F3 npd = vnormal(P1, P2, P3);
        float loss = fabsf(ng.x - npd.x) + fabsf(ng.y - npd.y) + fabsf(ng.z - npd.z);

        // loss >= 0 -> float bits are order-preserving as uint
        unsigned int key = valid ? __float_as_uint(loss) : SENT_;
        keys[(size_t)b * G_ + g] = key;
        if (valid) atomicAdd(&lbins[key >> 24], 1u);
    }
    __syncthreads();
    unsigned int c = lbins[threadIdx.x];
    if (c) atomicAdd(&bins0[threadIdx.x], c);
}

// Radix passes 2 and 3. Every block redundantly re-derives the prefix from the
// previous-level histograms (LDS scan, ~1KB of L2-resident reads) -> no
// separate scan kernels on the critical path.
__global__ void __launch_bounds__(256)
hist_mid(const unsigned int* __restrict__ keys,
         const unsigned int* __restrict__ bins0, const unsigned int* __restrict__ bins1,
         unsigned int* __restrict__ out_bins, int level)
{
    __shared__ unsigned int s[258];
    __shared__ unsigned int lb[256];
    int t = threadIdx.x;
    lb[t] = 0;
    unsigned int b0, r1, tot0;
    scan_pick(bins0, s, NO_R_, b0, r1, tot0);
    unsigned int prefix = b0;
    int shift = 16;
    if (level == 2) {
        unsigned int b1, r2, tot1;
        scan_pick(bins1, s, r1, b1, r2, tot1);
        prefix = (b0 << 8) | b1;
        shift = 8;
    }
    // lb zero-init is visible: written before scan_pick's __syncthreads
    int stride = gridDim.x * 256;
    for (int i = blockIdx.x * 256 + t; i < N_; i += stride) {
        unsigned int k = keys[i];
        // valid keys have top byte <= 0x40 (loss <= 6), sentinel 0xFF never matches
        if ((k >> (shift + 8)) == prefix)
            atomicAdd(&lb[(k >> shift) & 0xFFu], 1u);
    }
    __syncthreads();
    unsigned int c = lb[t];
    if (c) atomicAdd(&out_bins[t], c);
}

// Fused radix pass 4 + top-K sum + finalize.
// For the selected 24-bit-prefix bin, accumulate per-4th-byte counts AND value
// sums; sum everything strictly above the bin directly. Keys sharing all 4
// bytes are bit-identical floats, so the partial byte contributes count*value
// exactly. Last-done block finalizes.
__global__ void __launch_bounds__(256)
final_kernel(const unsigned int* __restrict__ keys,
             const unsigned int* __restrict__ bins0, const unsigned int* __restrict__ bins1,
             const unsigned int* __restrict__ bins2,
             unsigned int* __restrict__ bins3, double* __restrict__ binsum3,
             double* __restrict__ sumhi, unsigned int* __restrict__ cnthi,
             unsigned int* __restrict__ donecnt, float* __restrict__ out, int nblocks)
{
    __shared__ unsigned int s[258];
    __shared__ unsigned int lc[256];
    __shared__ float lsf[256];
    int t = threadIdx.x;
    lc[t] = 0; lsf[t] = 0.0f;
    unsigned int b0, r1, tot0; scan_pick(bins0, s, NO_R_, b0, r1, tot0);
    unsigned int b1, r2, tot1; scan_pick(bins1, s, r1, b1, r2, tot1);
    unsigned int b2, r3, tot2; scan_pick(bins2, s, r2, b2, r3, tot2);
    unsigned int p24 = (b0 << 16) | (b1 << 8) | b2;

    double lsum = 0.0;
    unsigned int lcnt = 0;
    int stride = gridDim.x * 256;
    for (int i = blockIdx.x * 256 + t; i < N_; i += stride) {
        unsigned int k = keys[i];
        if (k == SENT_) continue;
        unsigned int hi = k >> 8;
        if (hi > p24) { lsum += (double)__uint_as_float(k); lcnt++; }
        else if (hi == p24) {
            atomicAdd(&lc[k & 0xFFu], 1u);
            atomicAdd(&lsf[k & 0xFFu], __uint_as_float(k));
        }
    }
    for (int off = 32; off > 0; off >>= 1) {
        lsum += __shfl_down(lsum, off, 64);
        lcnt += __shfl_down(lcnt, off, 64);
    }
    __shared__ double wsum[4];
    __shared__ unsigned int wcnt[4];
    int lane = t & 63, wv = t >> 6;
    if (lane == 0) { wsum[wv] = lsum; wcnt[wv] = lcnt; }
    __syncthreads();
    if (t == 0) {
        atomicAdd(sumhi, wsum[0] + wsum[1] + wsum[2] + wsum[3]);
        atomicAdd(cnthi, wcnt[0] + wcnt[1] + wcnt[2] + wcnt[3]);
    }
    unsigned int c = lc[t];
    if (c) {
        atomicAdd(&bins3[t], c);
        atomicAdd(&binsum3[t], (double)lsf[t]);
    }
    __syncthreads();
    __shared__ unsigned int isLast;
    if (t == 0) {
        __threadfence();
        isLast = (atomicAdd(donecnt, 1u) == (unsigned int)(nblocks - 1)) ? 1u : 0u;
    }
    __syncthreads();
    if (isLast) {
        __shared__ double snap[256];
        // coherent parallel snapshot of the global bin state
        unsigned int bc = atomicAdd(&bins3[t], 0u);
        double bs = atomicAdd(&binsum3[t], 0.0);
        lc[t] = bc; snap[t] = bs;
        __syncthreads();
        if (t == 0) {
            unsigned int K = tot0 - tot0 / 4u;
            if (tot0 == 0u || K == 0u) {
                out[0] = 0.0f;
            } else {
                double shi = atomicAdd(sumhi, 0.0);
                unsigned int chi = atomicAdd(cnthi, 0u);
                unsigned int need = K - chi;   // in [1, m] by construction
                unsigned int cab = 0;
                double sab = 0.0;
                int b3 = 0;
                for (int by = 255; by >= 0; --by) {
                    unsigned int cc = lc[by];
                    if (cab + cc >= need) { b3 = by; break; }
                    cab += cc; sab += snap[by];
                }
                float tv = __uint_as_float((p24 << 8) | (unsigned int)b3);
                double res = shi + sab + (double)(need - cab) * (double)tv;
                out[0] = (float)(res / (double)K);
            }
        }
    }
}

extern "C" void kernel_launch(void* const* d_in, const int* in_sizes, int n_in,
                              void* d_out, int out_size, void* d_ws, size_t ws_size,
                              hipStream_t stream)
{
    const float* pred = (const float*)d_in[0];
    const float* targ = (const float*)d_in[1];
    // d_in[2] = mask: unused (only used in host-side index sampling)
    const float* intr = (const float*)d_in[3];
    const int* p1 = (const int*)d_in[4];
    const int* p2 = (const int*)d_in[5];
    const int* p3 = (const int*)d_in[6];
    float* out = (float*)d_out;

    unsigned char* ws = (unsigned char*)d_ws;
    unsigned int* bins0 = (unsigned int*)(ws + OFF_BINS0);
    unsigned int* bins1 = (unsigned int*)(ws + OFF_BINS1);
    unsigned int* bins2 = (unsigned int*)(ws + OFF_BINS2);
    unsigned int* bins3 = (unsigned int*)(ws + OFF_BINS3);
    double* binsum3 = (double*)(ws + OFF_BINSUM3);
    double* sumhi = (double*)(ws + OFF_SUMHI);
    unsigned int* cnthi = (unsigned int*)(ws + OFF_CNTHI);
    unsigned int* donecnt = (unsigned int*)(ws + OFF_DONE);
    unsigned int* keys = (unsigned int*)(ws + OFF_KEYS);

    hipMemsetAsync(d_ws, 0, ZERO_BYTES, stream);

    compute_kernel<<<GBLK_ * B_, 256, 0, stream>>>(pred, targ, intr, p1, p2, p3, keys, bins0);

    const int hblocks = 512;
    hist_mid<<<hblocks, 256, 0, stream>>>(keys, bins0, bins1, bins1, 1);
    hist_mid<<<hblocks, 256, 0, stream>>>(keys, bins0, bins1, bins2, 2);

    const int fblocks = 512;
    final_kernel<<<fblocks, 256, 0, stream>>>(keys, bins0, bins1, bins2, bins3, binsum3,
                                              sumhi, cnthi, donecnt, out, fblocks);
}

// Round 3
// 170.843 us; speedup vs baseline: 1.2051x; 1.2051x over previous
//
#include <hip/hip_runtime.h>

// Problem constants (match reference)
#define B_ 8
#define H_ 512
#define W_ 1024
#define HW_ (H_ * W_)
#define G_ 104857
#define N_ (B_ * G_)
#define GBLK_ 410               // ceil(G_/256)
#define EPS_ 1e-6f
#define DCOS_ 0.867f
#define DDIFF_ 0.005f
#define DZ_ 1e-5f

// Fine linear histogram over loss in [0, 2*sqrt(3)~3.4641]. 2048 bins of
// width ~1.95e-3. Quantile-bin average approximation error <= bin width
// (~2e-3), 20x under the 4.1e-2 absmax threshold.
#define NBIN_ 2048
#define BINSCALE_ 512.0f        // 3.4641*512 = 1773.6 < 2048

// ws layout (byte offsets); [0, ZERO_BYTES) zeroed by one memset per call
#define OFF_CNT  0                  // NBIN_ u32
#define OFF_SUM  (NBIN_ * 4)        // NBIN_ f32
#define ZERO_BYTES (NBIN_ * 8)

struct F3 { float x, y, z; };
__device__ __forceinline__ F3 f3sub(F3 a, F3 b) { return {a.x - b.x, a.y - b.y, a.z - b.z}; }
__device__ __forceinline__ float f3dot(F3 a, F3 b) { return a.x * b.x + a.y * b.y + a.z * b.z; }
__device__ __forceinline__ F3 f3cross(F3 a, F3 b) {
    return {a.y * b.z - a.z * b.y, a.z * b.x - a.x * b.z, a.x * b.y - a.y * b.x};
}

// loss + valid per triplet; fused fine histogram (count + value-sum).
// 1D grid; blockIdx.x & 7 = image -> same image stays on one XCD (round-robin
// block->XCD dispatch): its ~8 MB of depth maps mostly fits that XCD's L2.
__global__ void __launch_bounds__(256)
compute_kernel(const float* __restrict__ pred, const float* __restrict__ targ,
               const float* __restrict__ intr,
               const int* __restrict__ p1, const int* __restrict__ p2,
               const int* __restrict__ p3,
               unsigned int* __restrict__ gcnt, float* __restrict__ gsum)
{
    __shared__ unsigned int hc[NBIN_];
    __shared__ float hs[NBIN_];
    for (int i = threadIdx.x; i < NBIN_; i += 256) { hc[i] = 0u; hs[i] = 0.0f; }
    __syncthreads();

    int b = blockIdx.x & 7;
    int g = (blockIdx.x >> 3) * 256 + threadIdx.x;
    if (g < G_) {
        float f  = intr[b * 9 + 0];   // fx used for both x and y (per reference)
        float u0 = intr[b * 9 + 2];
        float v0 = intr[b * 9 + 5];
        float invf = 1.0f / f;
        int i1 = p1[b * G_ + g], i2 = p2[b * G_ + g], i3 = p3[b * G_ + g];
        const float* tb = targ + (size_t)b * HW_;
        const float* pb = pred + (size_t)b * HW_;

        auto unproj = [&](const float* dmap, int i) -> F3 {
            float d = dmap[i];
            float u = (float)(i & (W_ - 1));
            float v = (float)(i >> 10);
            F3 P;
            P.x = (u - u0) * d * invf;
            P.y = (v - v0) * d * invf;
            P.z = d;
            return P;
        };

        F3 G1 = unproj(tb, i1), G2 = unproj(tb, i2), G3 = unproj(tb, i3);
        F3 P1 = unproj(pb, i1), P2 = unproj(pb, i2), P3 = unproj(pb, i3);

        // ---- filter_mask on GT groups (division-free comparisons) ----
        F3 d12 = f3sub(G2, G1), d13 = f3sub(G3, G1), d23 = f3sub(G3, G2);
        float e11 = f3dot(d12, d12), e22 = f3dot(d13, d13), e33 = f3dot(d23, d23);
        float e12 = f3dot(d12, d13), e13 = f3dot(d12, d23), e23 = f3dot(d13, d23);
        float q1 = sqrtf(e11), q2 = sqrtf(e22), q3 = sqrtf(e33);
        // |e|/(nm+EPS) > DCOS  <=>  |e| > DCOS*(nm+EPS)   (nm >= 0)
        int cnt = 0;
        cnt += (e11 > DCOS_ * (q1 * q1 + EPS_)) ? 1 : 0;
        cnt += (e22 > DCOS_ * (q2 * q2 + EPS_)) ? 1 : 0;
        cnt += (e33 > DCOS_ * (q3 * q3 + EPS_)) ? 1 : 0;
        cnt += (fabsf(e12) > DCOS_ * (q1 * q2 + EPS_)) ? 2 : 0;  // symmetric off-diag
        cnt += (fabsf(e13) > DCOS_ * (q1 * q3 + EPS_)) ? 2 : 0;
        cnt += (fabsf(e23) > DCOS_ * (q2 * q3 + EPS_)) ? 2 : 0;
        bool mask_cos = cnt > 3;
        bool mask_pad = (G1.z > DZ_) && (G2.z > DZ_) && (G3.z > DZ_);
        bool mx = (fabsf(d12.x) < DDIFF_) || (fabsf(d13.x) < DDIFF_) || (fabsf(d23.x) < DDIFF_);
        bool my = (fabsf(d12.y) < DDIFF_) || (fabsf(d13.y) < DDIFF_) || (fabsf(d23.y) < DDIFF_);
        bool mz = (fabsf(d12.z) < DDIFF_) || (fabsf(d13.z) < DDIFF_) || (fabsf(d23.z) < DDIFF_);
        bool valid = mask_pad && !((mx && my && mz) || mask_cos);

        if (valid) {
            // faithful replication of the reference's boolean-mask broadcast quirk
            bool c0 = (P1.z == 0.0f), c1 = (P2.z == 0.0f), c2 = (P3.z == 0.0f);
            if (c0) { P1.x = 1e-4f; P2.x = 1e-4f; P3.x = 1e-4f; }
            if (c1) { P1.y = 1e-4f; P2.y = 1e-4f; P3.y = 1e-4f; }
            if (c2) { P1.z = 1e-4f; P2.z = 1e-4f; P3.z = 1e-4f; }

            auto vnormal = [](F3 A, F3 Bp, F3 C) -> F3 {
                F3 a = f3sub(Bp, A), c = f3sub(C, A);
                F3 n = f3cross(a, c);
                float d = f3dot(n, n);
                // d==0 -> n==0 -> reference divides 0 by EPS -> 0; r=0 matches
                float r = (d > 0.0f) ? rsqrtf(d) : 0.0f;
                return F3{n.x * r, n.y * r, n.z * r};
            };
            F3 ng = vnormal(G1, G2, G3);
            F3 npd = vnormal(P1, P2, P3);
            float loss = fabsf(ng.x - npd.x) + fabsf(ng.y - npd.y) + fabsf(ng.z - npd.z);

            int bin = (int)(loss * BINSCALE_);
            bin = min(max(bin, 0), NBIN_ - 1);
            atomicAdd(&hc[bin], 1u);
            atomicAdd(&hs[bin], loss);
        }
    }
    __syncthreads();
    for (int i = threadIdx.x; i < NBIN_; i += 256) {
        unsigned int c = hc[i];
        if (c) {
            atomicAdd(&gcnt[i], c);
            atomicAdd(&gsum[i], hs[i]);
        }
    }
}

// Single block. Scan 2048 (count,sum) bins; drop bottom n/4 (partial bin via
// bin-average approximation); mean of the rest.
__global__ void __launch_bounds__(256)
finalize_kernel(const unsigned int* __restrict__ gcnt, const float* __restrict__ gsum,
                float* __restrict__ out)
{
    __shared__ unsigned int scc[256];
    __shared__ double scs[256];
    int t = threadIdx.x;
    const int PB = NBIN_ / 256;  // 8 bins per thread
    unsigned int lc[PB];
    double lsv[PB];
    unsigned int lcnt = 0;
    double lsum = 0.0;
    for (int j = 0; j < PB; ++j) {
        lc[j] = gcnt[t * PB + j];
        lsv[j] = (double)gsum[t * PB + j];
        lcnt += lc[j];
        lsum += lsv[j];
    }
    scc[t] = lcnt; scs[t] = lsum;
    __syncthreads();
    for (int off = 1; off < 256; off <<= 1) {
        unsigned int ac = (t >= off) ? scc[t - off] : 0u;
        double as = (t >= off) ? scs[t - off] : 0.0;
        __syncthreads();
        scc[t] += ac; scs[t] += as;
        __syncthreads();
    }
    unsigned int tot = scc[255];
    double total_sum = scs[255];
    if (tot == 0u) { if (t == 0) out[0] = 0.0f; return; }
    unsigned int r = tot / 4u;         // dropped count
    unsigned int K = tot - r;          // kept count (>=1)
    unsigned int cprev = (t == 0) ? 0u : scc[t - 1];
    double sprev = (t == 0) ? 0.0 : scs[t - 1];
    if (scc[t] > r && cprev <= r) {    // unique owner of the quantile bin range
        unsigned int c = cprev;
        double s = sprev;
        double dropped = 0.0;
        for (int j = 0; j < PB; ++j) {
            if (c + lc[j] > r) {       // threshold bin (lc[j] > 0 here)
                double avg = lsv[j] / (double)lc[j];
                dropped = s + (double)(r - c) * avg;
                break;
            }
            c += lc[j]; s += lsv[j];
        }
        out[0] = (float)((total_sum - dropped) / (double)K);
    }
}

extern "C" void kernel_launch(void* const* d_in, const int* in_sizes, int n_in,
                              void* d_out, int out_size, void* d_ws, size_t ws_size,
                              hipStream_t stream)
{
    const float* pred = (const float*)d_in[0];
    const float* targ = (const float*)d_in[1];
    // d_in[2] = mask: unused (only used in host-side index sampling)
    const float* intr = (const float*)d_in[3];
    const int* p1 = (const int*)d_in[4];
    const int* p2 = (const int*)d_in[5];
    const int* p3 = (const int*)d_in[6];
    float* out = (float*)d_out;

    unsigned char* ws = (unsigned char*)d_ws;
    unsigned int* gcnt = (unsigned int*)(ws + OFF_CNT);
    float* gsum = (float*)(ws + OFF_SUM);

    hipMemsetAsync(d_ws, 0, ZERO_BYTES, stream);

    compute_kernel<<<GBLK_ * B_, 256, 0, stream>>>(pred, targ, intr, p1, p2, p3, gcnt, gsum);
    finalize_kernel<<<1, 256, 0, stream>>>(gcnt, gsum, out);
}